// Round 14
// baseline (45.315 us; speedup 1.0000x reference)
//
#include <hip/hip_runtime.h>
#include <stdint.h>

// VQ-VAE quantization: B=131072 rows of z (D=64) vs N_E=1024 codes.
// Outputs (flat f32): z_q [131072*64] | loss [1] | idx [131072] | var(idx,ddof=1) [1]
//
// R14 = R13 + forced VGPR headroom (__launch_bounds__(512,1); occupancy is
// LDS-capped at 1 block/CU regardless) + explicit 3-slot register pipeline
// (tile t+2's 5 ds_reads issued ~2 compute-blocks before use) + min3-shaped
// key trees. R3/R5/R6's pipelines were silently collapsed by 64-88 VGPR caps;
// this is the first pipeline attempt with an honest register budget.
// Math identical to R13 (verified): 32x32x16 MFMA, K extended to 80 where the
// 5th MFMA's A-column carries ||e||^2 against a unit B-vector, C-in = 0.5.
// key = (float_bits(0.5+||e||^2-2z.e) & ~1023) | code ; unsigned min = argmin.

typedef __attribute__((ext_vector_type(8))) __bf16 bf16x8;
typedef __attribute__((ext_vector_type(4))) float f32x4;
typedef __attribute__((ext_vector_type(16))) float f32x16;

#define OUT_LOSS 8388608
#define OUT_IDX  8388609
#define OUT_VAR  8519681

// workspace layout (bytes)
#define WS_LOSS  0          // float[256] per-block loss partials
#define WS_S1    4096       // int[256] sum(idx)
#define WS_S2    8192       // int[256] sum(idx^2)
#define WS_EFRAG 12288      // bf16x8[32 tiles * 4 ksteps * 64 lanes] = 128 KB
#define WS_A4    143360     // bf16x8[32 tiles * 32 lanes] ee-column = 16 KB

__device__ __forceinline__ void gld_lds16(const void* g, void* l) {
  __builtin_amdgcn_global_load_lds(
      (const __attribute__((address_space(1))) unsigned*)g,
      (__attribute__((address_space(3))) unsigned*)l, 16, 0, 0);
}

// ---- K0: prep codebook fragments (32x32x16 A-layout) -----------------------
// A-frag: lane l holds code row (t*32 + (l&31)), k = ks*16 + (l>>5)*8 + i.
// Values are -2*e. A4 (K-extension): lanes<32 hold elem0 = bf16(||e||^2).
__global__ void vq_prep(const float* __restrict__ emb, char* __restrict__ ws) {
  bf16x8* efrag = (bf16x8*)(ws + WS_EFRAG);
  bf16x8* a4 = (bf16x8*)(ws + WS_A4);
  const int t = blockIdx.x;    // tile 0..31 (32 codes each)
  const int l = threadIdx.x;   // 0..63
  const int n = t * 32 + (l & 31);
  const int kb = (l >> 5) * 8;
  const float* er = emb + n * 64;
#pragma unroll
  for (int ks = 0; ks < 4; ++ks) {
    bf16x8 h;
#pragma unroll
    for (int i = 0; i < 8; ++i) h[i] = (__bf16)(-2.0f * er[ks * 16 + kb + i]);
    efrag[(t * 4 + ks) * 64 + l] = h;
  }
  if (l < 32) {
    float s = 0.f;
#pragma unroll
    for (int d = 0; d < 64; ++d) s += er[d] * er[d];
    bf16x8 h;
#pragma unroll
    for (int i = 0; i < 8; ++i) h[i] = (__bf16)0.f;
    h[0] = (__bf16)s;
    a4[t * 32 + l] = h;
  }
}

// ---- K1: distances + argmin + fused epilogue -------------------------------
// 256 blocks x 512 thr (8 waves); wave w owns rows blockIdx*512 + w*64 .. +63.
__global__ void __launch_bounds__(512, 1) vq_main(
    const float* __restrict__ z, const float* __restrict__ emb,
    float* __restrict__ out, char* __restrict__ ws) {
  __shared__ char sfrag[131072];   // full codebook A-frags, resident
  __shared__ char sa4[16384];      // ee K-extension column
  __shared__ float sL[8];
  __shared__ int sA[8], sB[8];

  const int tid = threadIdx.x;
  const int wave = tid >> 6, lane = tid & 63;
  const int l31 = lane & 31, lh = lane >> 5;
  const int rb = blockIdx.x * 512 + wave * 64;

  // one-shot staging: 128K frags (16 passes) + 16K A4 (2 passes)
#pragma unroll
  for (int i = 0; i < 16; ++i)
    gld_lds16(ws + WS_EFRAG + i * 8192 + wave * 1024 + lane * 16,
              sfrag + i * 8192 + wave * 1024);
#pragma unroll
  for (int i = 0; i < 2; ++i)
    gld_lds16(ws + WS_A4 + i * 8192 + wave * 1024 + lane * 16,
              sa4 + i * 8192 + wave * 1024);

  // z B-fragments: col = lane&31 -> z-row rb + rg*32 + (lane&31);
  // k = ks*16 + (lane>>5)*8 + i. Lane covers 32 of the row's 64 dims.
  bf16x8 zb[2][4];
  float zzp[2];
#pragma unroll
  for (int rg = 0; rg < 2; ++rg) {
    const float* zp = z + (size_t)(rb + rg * 32 + l31) * 64 + lh * 8;
    float s = 0.f;
#pragma unroll
    for (int ks = 0; ks < 4; ++ks) {
      f32x4 v0 = *(const f32x4*)(zp + ks * 16);
      f32x4 v1 = *(const f32x4*)(zp + ks * 16 + 4);
      bf16x8 h;
#pragma unroll
      for (int i = 0; i < 4; ++i) {
        h[i] = (__bf16)v0[i]; h[4 + i] = (__bf16)v1[i];
        s += v0[i] * v0[i] + v1[i] * v1[i];
      }
      zb[rg][ks] = h;
    }
    zzp[rg] = s;
  }
  // B4 unit vector: k=0 slot only (lanes<32, elem0)
  bf16x8 zb4;
#pragma unroll
  for (int i = 0; i < 8; ++i) zb4[i] = (__bf16)0.f;
  if (lh == 0) zb4[0] = (__bf16)1.0f;

  f32x16 half16;
#pragma unroll
  for (int i = 0; i < 16; ++i) half16[i] = 0.5f;

  asm volatile("s_waitcnt vmcnt(0)" ::: "memory");
  __syncthreads();                  // staging visible; the ONLY barrier

  const bf16x8* fr = (const bf16x8*)sfrag;
  const bf16x8* a4 = (const bf16x8*)sa4;
  unsigned rk0 = 0xFFFFFFFFu, rk1 = 0xFFFFFFFFu;
  const unsigned vbase = 4u * (unsigned)lh;

  // 3-slot register pipeline: slot = {A0..A3, A4} = 20 VGPR; tile t+2's
  // reads are issued two compute-blocks (~2x(10 MFMA + keys)) before use.
  bf16x8 S[3][5];
#define LOADSLOT(s_, t_)                                                     \
  {                                                                          \
    S[s_][0] = fr[((t_) * 4 + 0) * 64 + lane];                               \
    S[s_][1] = fr[((t_) * 4 + 1) * 64 + lane];                               \
    S[s_][2] = fr[((t_) * 4 + 2) * 64 + lane];                               \
    S[s_][3] = fr[((t_) * 4 + 3) * 64 + lane];                               \
    S[s_][4] = a4[(t_) * 32 + l31];                                          \
  }
#define COMPUTE(s_, t_)                                                      \
  {                                                                          \
    __builtin_amdgcn_s_setprio(1);                                           \
    f32x16 c0 = __builtin_amdgcn_mfma_f32_32x32x16_bf16(S[s_][0], zb[0][0], half16, 0, 0, 0); \
    c0 = __builtin_amdgcn_mfma_f32_32x32x16_bf16(S[s_][1], zb[0][1], c0, 0, 0, 0); \
    c0 = __builtin_amdgcn_mfma_f32_32x32x16_bf16(S[s_][2], zb[0][2], c0, 0, 0, 0); \
    c0 = __builtin_amdgcn_mfma_f32_32x32x16_bf16(S[s_][3], zb[0][3], c0, 0, 0, 0); \
    c0 = __builtin_amdgcn_mfma_f32_32x32x16_bf16(S[s_][4], zb4, c0, 0, 0, 0);      \
    f32x16 c1 = __builtin_amdgcn_mfma_f32_32x32x16_bf16(S[s_][0], zb[1][0], half16, 0, 0, 0); \
    c1 = __builtin_amdgcn_mfma_f32_32x32x16_bf16(S[s_][1], zb[1][1], c1, 0, 0, 0); \
    c1 = __builtin_amdgcn_mfma_f32_32x32x16_bf16(S[s_][2], zb[1][2], c1, 0, 0, 0); \
    c1 = __builtin_amdgcn_mfma_f32_32x32x16_bf16(S[s_][3], zb[1][3], c1, 0, 0, 0); \
    c1 = __builtin_amdgcn_mfma_f32_32x32x16_bf16(S[s_][4], zb4, c1, 0, 0, 0);      \
    __builtin_amdgcn_s_setprio(0);                                           \
    unsigned q[16];                                                          \
    _Pragma("unroll")                                                        \
    for (int r = 0; r < 16; ++r)                                             \
      q[r] = (__float_as_uint(c0[r]) & 0xFFFFFC00u) | (unsigned)((r & 3) + 8 * (r >> 2)); \
    {                                                                        \
      unsigned m0 = min(min(q[0], q[1]), q[2]);                              \
      unsigned m1 = min(min(q[3], q[4]), q[5]);                              \
      unsigned m2 = min(min(q[6], q[7]), q[8]);                              \
      unsigned m3 = min(min(q[9], q[10]), q[11]);                            \
      unsigned m4 = min(min(q[12], q[13]), q[14]);                           \
      unsigned mm = min(min(min(m0, m1), m2), min(min(m3, m4), q[15]));      \
      rk0 = min(rk0, mm + vbase + (unsigned)((t_) * 32));                    \
    }                                                                        \
    _Pragma("unroll")                                                        \
    for (int r = 0; r < 16; ++r)                                             \
      q[r] = (__float_as_uint(c1[r]) & 0xFFFFFC00u) | (unsigned)((r & 3) + 8 * (r >> 2)); \
    {                                                                        \
      unsigned m0 = min(min(q[0], q[1]), q[2]);                              \
      unsigned m1 = min(min(q[3], q[4]), q[5]);                              \
      unsigned m2 = min(min(q[6], q[7]), q[8]);                              \
      unsigned m3 = min(min(q[9], q[10]), q[11]);                            \
      unsigned m4 = min(min(q[12], q[13]), q[14]);                           \
      unsigned mm = min(min(min(m0, m1), m2), min(min(m3, m4), q[15]));      \
      rk1 = min(rk1, mm + vbase + (unsigned)((t_) * 32));                    \
    }                                                                        \
  }

  LOADSLOT(0, 0);
  LOADSLOT(1, 1);
  for (int it = 0; it < 10; ++it) {    // t = 3*it; computes tiles 0..29
    const int t = 3 * it;
    LOADSLOT(2, t + 2);
    COMPUTE(0, t);
    LOADSLOT(0, t + 3);
    COMPUTE(1, t + 1);
    LOADSLOT(1, t + 4);
    COMPUTE(2, t + 2);
  }
  COMPUTE(0, 30);
  COMPUTE(1, 31);
#undef LOADSLOT
#undef COMPUTE

  // combine the two code-offset halves (lane <-> lane^32); complete zz
  rk0 = min(rk0, (unsigned)__shfl_xor((int)rk0, 32, 64));
  rk1 = min(rk1, (unsigned)__shfl_xor((int)rk1, 32, 64));
  float zz0 = zzp[0] + __shfl_xor(zzp[0], 32, 64);
  float zz1 = zzp[1] + __shfl_xor(zzp[1], 32, 64);

  // epilogue: lane handles row rb + lane (lane<32 -> rg0, else rg1)
  const unsigned key = (lane < 32) ? rk0 : rk1;
  const float zzv = (lane < 32) ? zz0 : zz1;
  const unsigned idx = key & 1023u;
  const size_t rowg = (size_t)rb + lane;
  const f32x4* ep = (const f32x4*)(emb + (size_t)idx * 64);
  f32x4* op = (f32x4*)(out + rowg * 64);
#pragma unroll
  for (int c = 0; c < 16; ++c) op[c] = ep[c];
  out[OUT_IDX + rowg] = (float)idx;

  // per-lane partials: d = zz + (0.5 + ee - 2 z.e)_min - 0.5
  float ls = zzv + __uint_as_float(key & 0xFFFFFC00u) - 0.5f;
  int s1 = (int)idx;
  int s2 = (int)(idx * idx);
#pragma unroll
  for (int off = 1; off < 64; off <<= 1) {
    ls += __shfl_xor(ls, off, 64);
    s1 += __shfl_xor(s1, off, 64);
    s2 += __shfl_xor(s2, off, 64);
  }
  if (lane == 0) { sL[wave] = ls; sA[wave] = s1; sB[wave] = s2; }
  __syncthreads();
  if (tid == 0) {
    float L = 0; int a = 0, b = 0;
#pragma unroll
    for (int w = 0; w < 8; ++w) { L += sL[w]; a += sA[w]; b += sB[w]; }
    ((float*)(ws + WS_LOSS))[blockIdx.x] = L;
    ((int*)(ws + WS_S1))[blockIdx.x] = a;
    ((int*)(ws + WS_S2))[blockIdx.x] = b;
  }
}

// ---- K2: final scalar reduce over 256 block partials -----------------------
__global__ void vq_final(float* __restrict__ out, const char* __restrict__ ws) {
  const int t = threadIdx.x;   // 256 threads, 1 partial each
  const float* lp = (const float*)(ws + WS_LOSS);
  const int* p1 = (const int*)(ws + WS_S1);
  const int* p2 = (const int*)(ws + WS_S2);
  double L = (double)lp[t];
  long long a = (long long)p1[t];
  long long b = (long long)p2[t];
#pragma unroll
  for (int off = 1; off < 64; off <<= 1) {
    L += __shfl_xor(L, off, 64);
    a += __shfl_xor(a, off, 64);
    b += __shfl_xor(b, off, 64);
  }
  __shared__ double sLf[4];
  __shared__ long long sAf[4], sBf[4];
  const int wave = t >> 6, lane = t & 63;
  if (lane == 0) { sLf[wave] = L; sAf[wave] = a; sBf[wave] = b; }
  __syncthreads();
  if (t == 0) {
    double Lt = 0; long long at = 0, bt = 0;
#pragma unroll
    for (int w = 0; w < 4; ++w) { Lt += sLf[w]; at += sAf[w]; bt += sBf[w]; }
    // loss = (beta + 1) * mean((z_q - z)^2), beta = 0.25
    out[OUT_LOSS] = (float)(1.25 * Lt / 8388608.0);
    // var(idx, ddof=1) exact: (n*S2 - S1^2) / (n*(n-1))
    long long num = bt * 131072LL - at * at;
    out[OUT_VAR] = (float)((double)num / (131072.0 * 131071.0));
  }
}

extern "C" void kernel_launch(void* const* d_in, const int* in_sizes, int n_in,
                              void* d_out, int out_size, void* d_ws, size_t ws_size,
                              hipStream_t stream) {
  (void)in_sizes; (void)n_in; (void)out_size; (void)ws_size;
  const float* z = (const float*)d_in[0];
  const float* emb = (const float*)d_in[1];
  float* out = (float*)d_out;
  char* ws = (char*)d_ws;
  vq_prep<<<32, 64, 0, stream>>>(emb, ws);
  vq_main<<<256, 512, 0, stream>>>(z, emb, out, ws);
  vq_final<<<1, 256, 0, stream>>>(out, ws);
}